// Round 1
// baseline (729.186 us; speedup 1.0000x reference)
//
#include <hip/hip_runtime.h>
#include <hip/hip_bf16.h>
#include <math.h>

#define B_N 8192
#define T_N 4
#define D_N 1024

typedef __bf16 bf16x8 __attribute__((ext_vector_type(8)));
typedef float f32x4 __attribute__((ext_vector_type(4)));

// ---- order-preserving float <-> uint map (for atomicMax on floats incl. negatives) ----
__device__ inline unsigned int f2u_ord(float f) {
    unsigned int b = __float_as_uint(f);
    return (b & 0x80000000u) ? ~b : (b | 0x80000000u);
}
__device__ inline float u2f_ord(unsigned int u) {
    unsigned int b = (u & 0x80000000u) ? (u & 0x7FFFFFFFu) : ~u;
    return __uint_as_float(b);
}

// round-to-nearest-even f32 -> bf16 (no NaN inputs here)
__device__ inline unsigned short f2bf(float f) {
    unsigned int u = __float_as_uint(f);
    unsigned int r = (u + 0x7FFFu + ((u >> 16) & 1u)) >> 16;
    return (unsigned short)r;
}

__global__ __launch_bounds__(256) void init_rowmax_kernel(unsigned int* __restrict__ rowmax) {
    int i = blockIdx.x * 256 + threadIdx.x;
    if (i < T_N * B_N) rowmax[i] = 0u;  // 0 maps below every real float
}

// in: [B][T][D] f32 ; out xn: [T][B][D] bf16 (normalized rows)
__global__ __launch_bounds__(256) void norm_kernel(const float* __restrict__ in,
                                                   unsigned short* __restrict__ xn) {
    const int row  = blockIdx.x * 4 + (threadIdx.x >> 6);  // row = b*T + t, in [0, B*T)
    const int lane = threadIdx.x & 63;
    const int b = row >> 2;
    const int t = row & 3;
    const float* src = in + (size_t)row * D_N;  // contiguous in input layout

    float4 v[4];
    float ss = 0.f;
#pragma unroll
    for (int i = 0; i < 4; ++i) {
        v[i] = reinterpret_cast<const float4*>(src)[lane + 64 * i];
        ss += v[i].x * v[i].x + v[i].y * v[i].y + v[i].z * v[i].z + v[i].w * v[i].w;
    }
#pragma unroll
    for (int off = 32; off; off >>= 1) ss += __shfl_xor(ss, off, 64);
    const float norm = sqrtf(ss);
    const float rn = 1.0f / fmaxf(norm, 1e-12f);

    unsigned short* dst = xn + ((size_t)t * B_N + b) * D_N;
#pragma unroll
    for (int i = 0; i < 4; ++i) {
        ushort4 o;
        o.x = f2bf(v[i].x * rn);
        o.y = f2bf(v[i].y * rn);
        o.z = f2bf(v[i].z * rn);
        o.w = f2bf(v[i].w * rn);
        reinterpret_cast<ushort4*>(dst)[lane + 64 * i] = o;
    }
}

#define GLOAD_LDS16(g, l)                                                              \
    __builtin_amdgcn_global_load_lds(                                                  \
        (const __attribute__((address_space(1))) unsigned int*)(g),                    \
        (__attribute__((address_space(3))) unsigned int*)(l), 16, 0, 0)

// C = Xn · Xnᵀ per view; fused per-row max over off-diagonal entries.
// 128x128 tile, BK=32, 4 waves (2x2), acc 4x4 of 16x16 frags per wave.
__global__ __launch_bounds__(256) void gemm_rowmax_kernel(const unsigned short* __restrict__ xn,
                                                          unsigned int* __restrict__ rowmax) {
    const int t  = blockIdx.z;
    const int bx = blockIdx.x;  // col block
    const int by = blockIdx.y;  // row block
    const unsigned short* X = xn + (size_t)t * B_N * D_N;

    __shared__ __align__(16) unsigned short As[128 * 32];
    __shared__ __align__(16) unsigned short Bs[128 * 32];

    const int tid  = threadIdx.x;
    const int lane = tid & 63;
    const int w    = tid >> 6;  // 0..3
    const int wr   = w >> 1, wc = w & 1;

    f32x4 acc[4][4];
#pragma unroll
    for (int m = 0; m < 4; ++m)
#pragma unroll
        for (int n = 0; n < 4; ++n) acc[m][n] = (f32x4){0.f, 0.f, 0.f, 0.f};

    // staging: each global_load_lds covers 16 rows x 32 cols (64 lanes x 16B)
    const int srow = w * 16 + (lane >> 2);
    const int scol = (lane & 3) * 8;
    const unsigned short* gA = X + (size_t)(by * 128 + srow) * D_N + scol;
    const unsigned short* gB = X + (size_t)(bx * 128 + srow) * D_N + scol;
    unsigned short* lA0 = &As[(w * 16) * 32];
    unsigned short* lA1 = &As[(w * 16 + 64) * 32];
    unsigned short* lB0 = &Bs[(w * 16) * 32];
    unsigned short* lB1 = &Bs[(w * 16 + 64) * 32];

    const int kg = (lane >> 4) * 8;  // k-offset of this lane's fragment

    for (int kt = 0; kt < D_N / 32; ++kt) {
        const unsigned short* ga = gA + kt * 32;
        const unsigned short* gb = gB + kt * 32;
        GLOAD_LDS16(ga, lA0);
        GLOAD_LDS16(ga + (size_t)64 * D_N, lA1);
        GLOAD_LDS16(gb, lB0);
        GLOAD_LDS16(gb + (size_t)64 * D_N, lB1);
        __syncthreads();  // drains vmcnt -> LDS tiles complete

        bf16x8 aF[4], bF[4];
#pragma unroll
        for (int m = 0; m < 4; ++m)
            aF[m] = *reinterpret_cast<const bf16x8*>(&As[(wr * 64 + m * 16 + (lane & 15)) * 32 + kg]);
#pragma unroll
        for (int n = 0; n < 4; ++n)
            bF[n] = *reinterpret_cast<const bf16x8*>(&Bs[(wc * 64 + n * 16 + (lane & 15)) * 32 + kg]);

#pragma unroll
        for (int m = 0; m < 4; ++m)
#pragma unroll
            for (int n = 0; n < 4; ++n)
                acc[m][n] = __builtin_amdgcn_mfma_f32_16x16x32_bf16(aF[m], bF[n], acc[m][n], 0, 0, 0);
        __syncthreads();  // protect LDS before next stage
    }

    // epilogue: per-row max over this block's 128 cols, diagonal excluded
    const int rbase = by * 128 + wr * 64;
    const int cbase = bx * 128 + wc * 64;
    unsigned int* rm = rowmax + t * B_N;
#pragma unroll
    for (int m = 0; m < 4; ++m) {
#pragma unroll
        for (int r = 0; r < 4; ++r) {
            const int row = rbase + m * 16 + (lane >> 4) * 4 + r;
            float mx = -2.0f;
#pragma unroll
            for (int n = 0; n < 4; ++n) {
                const int col = cbase + n * 16 + (lane & 15);
                float v = acc[m][n][r];
                if (col != row) mx = fmaxf(mx, v);
            }
            // reduce across the 16 lanes sharing (lane>>4)
#pragma unroll
            for (int off = 1; off < 16; off <<= 1) mx = fmaxf(mx, __shfl_xor(mx, off, 64));
            if ((lane & 15) == 0) atomicMax(&rm[row], f2u_ord(mx));
        }
    }
}

__global__ __launch_bounds__(256) void finish_kernel(const unsigned int* __restrict__ rowmax,
                                                     float* __restrict__ out) {
    __shared__ float sbuf[4];
    float s = 0.f;
    for (int i = threadIdx.x; i < T_N * B_N; i += 256) {
        float m  = u2f_ord(rowmax[i]);
        float d2 = fmaxf(2.0f - 2.0f * m, 0.0f);
        float dist = sqrtf(d2);
        s += logf(dist + 1e-12f);
    }
#pragma unroll
    for (int off = 32; off; off >>= 1) s += __shfl_xor(s, off, 64);
    const int w = threadIdx.x >> 6;
    if ((threadIdx.x & 63) == 0) sbuf[w] = s;
    __syncthreads();
    if (threadIdx.x == 0) {
        float tot = sbuf[0] + sbuf[1] + sbuf[2] + sbuf[3];
        out[0] = -tot / (float)(T_N * B_N);
    }
}

extern "C" void kernel_launch(void* const* d_in, const int* in_sizes, int n_in,
                              void* d_out, int out_size, void* d_ws, size_t ws_size,
                              hipStream_t stream) {
    const float* in = (const float*)d_in[0];
    unsigned short* xn = (unsigned short*)d_ws;                          // 64 MB bf16 [T][B][D]
    unsigned int* rowmax = (unsigned int*)((char*)d_ws + (size_t)T_N * B_N * D_N * 2);  // 128 KB
    float* out = (float*)d_out;

    init_rowmax_kernel<<<(T_N * B_N + 255) / 256, 256, 0, stream>>>(rowmax);
    norm_kernel<<<(B_N * T_N) / 4, 256, 0, stream>>>(in, xn);
    dim3 g(B_N / 128, B_N / 128, T_N);
    gemm_rowmax_kernel<<<g, 256, 0, stream>>>(xn, rowmax);
    finish_kernel<<<1, 256, 0, stream>>>(rowmax, out);
}

// Round 2
// 529.753 us; speedup vs baseline: 1.3765x; 1.3765x over previous
//
#include <hip/hip_runtime.h>
#include <hip/hip_bf16.h>
#include <math.h>

#define B_N 8192
#define T_N 4
#define D_N 1024

typedef __bf16 bf16x8 __attribute__((ext_vector_type(8)));
typedef float f32x4 __attribute__((ext_vector_type(4)));

// ---- order-preserving float <-> uint map (for atomicMax on floats incl. negatives) ----
__device__ inline unsigned int f2u_ord(float f) {
    unsigned int b = __float_as_uint(f);
    return (b & 0x80000000u) ? ~b : (b | 0x80000000u);
}
__device__ inline float u2f_ord(unsigned int u) {
    unsigned int b = (u & 0x80000000u) ? (u & 0x7FFFFFFFu) : ~u;
    return __uint_as_float(b);
}

// round-to-nearest-even f32 -> bf16 (no NaN inputs here)
__device__ inline unsigned short f2bf(float f) {
    unsigned int u = __float_as_uint(f);
    unsigned int r = (u + 0x7FFFu + ((u >> 16) & 1u)) >> 16;
    return (unsigned short)r;
}

__global__ __launch_bounds__(256) void init_rowmax_kernel(unsigned int* __restrict__ rowmax) {
    int i = blockIdx.x * 256 + threadIdx.x;
    if (i < T_N * B_N) rowmax[i] = 0u;  // 0 maps below every real float
}

// in: [B][T][D] f32 ; out xn: [T][B][D] bf16 (normalized rows)
__global__ __launch_bounds__(256) void norm_kernel(const float* __restrict__ in,
                                                   unsigned short* __restrict__ xn) {
    const int row  = blockIdx.x * 4 + (threadIdx.x >> 6);  // row = b*T + t, in [0, B*T)
    const int lane = threadIdx.x & 63;
    const int b = row >> 2;
    const int t = row & 3;
    const float* src = in + (size_t)row * D_N;  // contiguous in input layout

    float4 v[4];
    float ss = 0.f;
#pragma unroll
    for (int i = 0; i < 4; ++i) {
        v[i] = reinterpret_cast<const float4*>(src)[lane + 64 * i];
        ss += v[i].x * v[i].x + v[i].y * v[i].y + v[i].z * v[i].z + v[i].w * v[i].w;
    }
#pragma unroll
    for (int off = 32; off; off >>= 1) ss += __shfl_xor(ss, off, 64);
    const float norm = sqrtf(ss);
    const float rn = 1.0f / fmaxf(norm, 1e-12f);

    unsigned short* dst = xn + ((size_t)t * B_N + b) * D_N;
#pragma unroll
    for (int i = 0; i < 4; ++i) {
        ushort4 o;
        o.x = f2bf(v[i].x * rn);
        o.y = f2bf(v[i].y * rn);
        o.z = f2bf(v[i].z * rn);
        o.w = f2bf(v[i].w * rn);
        reinterpret_cast<ushort4*>(dst)[lane + 64 * i] = o;
    }
}

#define GLOAD_LDS16(g, l)                                                              \
    __builtin_amdgcn_global_load_lds(                                                  \
        (const __attribute__((address_space(1))) unsigned int*)(g),                    \
        (__attribute__((address_space(3))) unsigned int*)(l), 16, 0, 0)

// C = Xn · Xnᵀ per view (upper-triangle blocks only); fused per-row AND per-col max
// over off-diagonal entries. 128x128 tile, BK=32, 4 waves (2x2), acc 4x4 per wave.
// LDS slot swizzle: slot' = slot ^ ((row>>2)&3)  (rows are 64B = 4 x 16B slots);
// applied on the global SOURCE address (LDS dest linear, global_load_lds rule) and
// identically on the ds_read address.
__global__ __launch_bounds__(256) void gemm_rowmax_kernel(const unsigned short* __restrict__ xn,
                                                          unsigned int* __restrict__ rowmax) {
    const int bx = blockIdx.x;  // col block
    const int by = blockIdx.y;  // row block
    if (bx < by) return;        // symmetric: only upper triangle
    const int t  = blockIdx.z;
    const unsigned short* X = xn + (size_t)t * B_N * D_N;

    __shared__ __align__(16) unsigned short As[128 * 32];
    __shared__ __align__(16) unsigned short Bs[128 * 32];

    const int tid  = threadIdx.x;
    const int lane = tid & 63;
    const int w    = tid >> 6;  // 0..3
    const int wr   = w >> 1, wc = w & 1;

    f32x4 acc[4][4];
#pragma unroll
    for (int m = 0; m < 4; ++m)
#pragma unroll
        for (int n = 0; n < 4; ++n) acc[m][n] = (f32x4){0.f, 0.f, 0.f, 0.f};

    // staging: each global_load_lds covers 16 rows x 32 cols (64 lanes x 16B)
    // lane i -> LDS (row = base + i/4, slot = i&3); global source pre-swizzled:
    // chunk = (i&3) ^ ((i>>4)&3)   [ = slot ^ sigma(row), sigma(row)=(row>>2)&3 ]
    const int srow = w * 16 + (lane >> 2);
    const int scol = (((lane & 3) ^ ((lane >> 4) & 3)) * 8);
    const unsigned short* gA = X + (size_t)(by * 128 + srow) * D_N + scol;
    const unsigned short* gB = X + (size_t)(bx * 128 + srow) * D_N + scol;
    unsigned short* lA0 = &As[(w * 16) * 32];
    unsigned short* lA1 = &As[(w * 16 + 64) * 32];
    unsigned short* lB0 = &Bs[(w * 16) * 32];
    unsigned short* lB1 = &Bs[(w * 16 + 64) * 32];

    // fragment read: want k-chunk c = lane>>4 of row r; it lives at slot c ^ sigma(r),
    // sigma(r) = ((lane&15)>>2)&3 = (lane>>2)&3
    const int kg = (((lane >> 4) ^ ((lane >> 2) & 3)) * 8);

    for (int kt = 0; kt < D_N / 32; ++kt) {
        const unsigned short* ga = gA + kt * 32;
        const unsigned short* gb = gB + kt * 32;
        GLOAD_LDS16(ga, lA0);
        GLOAD_LDS16(ga + (size_t)64 * D_N, lA1);
        GLOAD_LDS16(gb, lB0);
        GLOAD_LDS16(gb + (size_t)64 * D_N, lB1);
        __syncthreads();  // drains vmcnt -> LDS tiles complete

        bf16x8 aF[4], bF[4];
#pragma unroll
        for (int m = 0; m < 4; ++m)
            aF[m] = *reinterpret_cast<const bf16x8*>(&As[(wr * 64 + m * 16 + (lane & 15)) * 32 + kg]);
#pragma unroll
        for (int n = 0; n < 4; ++n)
            bF[n] = *reinterpret_cast<const bf16x8*>(&Bs[(wc * 64 + n * 16 + (lane & 15)) * 32 + kg]);

#pragma unroll
        for (int m = 0; m < 4; ++m)
#pragma unroll
            for (int n = 0; n < 4; ++n)
                acc[m][n] = __builtin_amdgcn_mfma_f32_16x16x32_bf16(aF[m], bF[n], acc[m][n], 0, 0, 0);
        __syncthreads();  // protect LDS before next stage
    }

    // epilogue: C/D layout col = lane&15, row = (lane>>4)*4 + reg
    const int rbase = by * 128 + wr * 64;
    const int cbase = bx * 128 + wc * 64;
    unsigned int* rm = rowmax + t * B_N;

    // ---- row-max over this block's 128 cols (diag excluded) ----
#pragma unroll
    for (int m = 0; m < 4; ++m) {
#pragma unroll
        for (int r = 0; r < 4; ++r) {
            const int row = rbase + m * 16 + (lane >> 4) * 4 + r;
            float mx = -2.0f;
#pragma unroll
            for (int n = 0; n < 4; ++n) {
                const int col = cbase + n * 16 + (lane & 15);
                float v = acc[m][n][r];
                if (col != row) mx = fmaxf(mx, v);
            }
            // reduce across the 16 lanes sharing this row (within lane-group)
#pragma unroll
            for (int off = 1; off < 16; off <<= 1) mx = fmaxf(mx, __shfl_xor(mx, off, 64));
            if ((lane & 15) == 0) atomicMax(&rm[row], f2u_ord(mx));
        }
    }

    // ---- col-max over this block's 128 rows (covers the mirrored block) ----
#pragma unroll
    for (int n = 0; n < 4; ++n) {
        const int col = cbase + n * 16 + (lane & 15);
        float mx = -2.0f;
#pragma unroll
        for (int m = 0; m < 4; ++m) {
#pragma unroll
            for (int r = 0; r < 4; ++r) {
                const int row = rbase + m * 16 + (lane >> 4) * 4 + r;
                float v = acc[m][n][r];
                if (col != row) mx = fmaxf(mx, v);
            }
        }
        // reduce across the 4 lane-groups (same col, different row subsets)
        mx = fmaxf(mx, __shfl_xor(mx, 16, 64));
        mx = fmaxf(mx, __shfl_xor(mx, 32, 64));
        if ((lane >> 4) == 0) atomicMax(&rm[col], f2u_ord(mx));
    }
}

__global__ __launch_bounds__(256) void finish_kernel(const unsigned int* __restrict__ rowmax,
                                                     float* __restrict__ out) {
    __shared__ float sbuf[4];
    float s = 0.f;
    for (int i = threadIdx.x; i < T_N * B_N; i += 256) {
        float m  = u2f_ord(rowmax[i]);
        float d2 = fmaxf(2.0f - 2.0f * m, 0.0f);
        float dist = sqrtf(d2);
        s += logf(dist + 1e-12f);
    }
#pragma unroll
    for (int off = 32; off; off >>= 1) s += __shfl_xor(s, off, 64);
    const int w = threadIdx.x >> 6;
    if ((threadIdx.x & 63) == 0) sbuf[w] = s;
    __syncthreads();
    if (threadIdx.x == 0) {
        float tot = sbuf[0] + sbuf[1] + sbuf[2] + sbuf[3];
        out[0] = -tot / (float)(T_N * B_N);
    }
}

extern "C" void kernel_launch(void* const* d_in, const int* in_sizes, int n_in,
                              void* d_out, int out_size, void* d_ws, size_t ws_size,
                              hipStream_t stream) {
    const float* in = (const float*)d_in[0];
    unsigned short* xn = (unsigned short*)d_ws;                          // 64 MB bf16 [T][B][D]
    unsigned int* rowmax = (unsigned int*)((char*)d_ws + (size_t)T_N * B_N * D_N * 2);  // 128 KB
    float* out = (float*)d_out;

    init_rowmax_kernel<<<(T_N * B_N + 255) / 256, 256, 0, stream>>>(rowmax);
    norm_kernel<<<(B_N * T_N) / 4, 256, 0, stream>>>(in, xn);
    dim3 g(B_N / 128, B_N / 128, T_N);
    gemm_rowmax_kernel<<<g, 256, 0, stream>>>(xn, rowmax);
    finish_kernel<<<1, 256, 0, stream>>>(rowmax, out);
}

// Round 3
// 439.796 us; speedup vs baseline: 1.6580x; 1.2045x over previous
//
#include <hip/hip_runtime.h>
#include <hip/hip_bf16.h>
#include <math.h>

#define B_N 8192
#define T_N 4
#define D_N 1024
#define NB  32                 // 8192/256 row/col blocks
#define NT  16                 // 1024/64 K-tiles
#define TRI (NB * (NB + 1) / 2)  // 528 upper-triangle blocks per view

typedef __bf16 bf16x8 __attribute__((ext_vector_type(8)));
typedef float f32x4 __attribute__((ext_vector_type(4)));

// ---- order-preserving float <-> uint map ----
__device__ inline unsigned int f2u_ord(float f) {
    unsigned int b = __float_as_uint(f);
    return (b & 0x80000000u) ? ~b : (b | 0x80000000u);
}
__device__ inline float u2f_ord(unsigned int u) {
    unsigned int b = (u & 0x80000000u) ? (u & 0x7FFFFFFFu) : ~u;
    return __uint_as_float(b);
}

// round-to-nearest-even f32 -> bf16
__device__ inline unsigned short f2bf(float f) {
    unsigned int u = __float_as_uint(f);
    unsigned int r = (u + 0x7FFFu + ((u >> 16) & 1u)) >> 16;
    return (unsigned short)r;
}

__global__ __launch_bounds__(256) void init_rowmax_kernel(unsigned int* __restrict__ rowmax) {
    int i = blockIdx.x * 256 + threadIdx.x;
    if (i < T_N * B_N) rowmax[i] = 0u;
}

// in: [B][T][D] f32 ; out xn: [T][B][D] bf16 (normalized rows)
__global__ __launch_bounds__(256) void norm_kernel(const float* __restrict__ in,
                                                   unsigned short* __restrict__ xn) {
    const int row  = blockIdx.x * 4 + (threadIdx.x >> 6);
    const int lane = threadIdx.x & 63;
    const int b = row >> 2;
    const int t = row & 3;
    const float* src = in + (size_t)row * D_N;

    float4 v[4];
    float ss = 0.f;
#pragma unroll
    for (int i = 0; i < 4; ++i) {
        v[i] = reinterpret_cast<const float4*>(src)[lane + 64 * i];
        ss += v[i].x * v[i].x + v[i].y * v[i].y + v[i].z * v[i].z + v[i].w * v[i].w;
    }
#pragma unroll
    for (int off = 32; off; off >>= 1) ss += __shfl_xor(ss, off, 64);
    const float rn = 1.0f / fmaxf(sqrtf(ss), 1e-12f);

    unsigned short* dst = xn + ((size_t)t * B_N + b) * D_N;
#pragma unroll
    for (int i = 0; i < 4; ++i) {
        ushort4 o;
        o.x = f2bf(v[i].x * rn);
        o.y = f2bf(v[i].y * rn);
        o.z = f2bf(v[i].z * rn);
        o.w = f2bf(v[i].w * rn);
        reinterpret_cast<ushort4*>(dst)[lane + 64 * i] = o;
    }
}

#define GLOAD_LDS16(g, l)                                                              \
    __builtin_amdgcn_global_load_lds(                                                  \
        (const __attribute__((address_space(1))) unsigned int*)(g),                    \
        (__attribute__((address_space(3))) unsigned int*)(l), 16, 0, 0)

// Gram matrix upper-triangle, 256x256 tile, BK=64, 8 waves (2M x 4N), 8-phase-style
// schedule: per phase {12 ds_read_b128 | stage one 16KB unit | barrier | 16 MFMA |
// counted vmcnt | barrier}. LDS chunk-XOR swizzle (chunk ^= row&7), source-side
// pre-swizzled for linear global_load_lds dest. Fused row+col max epilogue.
__global__ __launch_bounds__(512) void gemm_rowmax_kernel(const unsigned short* __restrict__ xn,
                                                          unsigned int* __restrict__ rowmax) {
    const int t = blockIdx.z;
    // triangle decode: linear -> (by, bx), bx >= by
    int l = blockIdx.x, by = 0;
    while (l >= NB - by) { l -= NB - by; ++by; }
    const int bx = by + l;

    const unsigned short* X = xn + (size_t)t * B_N * D_N;

    __shared__ __align__(16) unsigned short lds[65536];  // 128 KiB: [2 buf][A 16K el | B 16K el]

    const int tid  = threadIdx.x;
    const int lane = tid & 63;
    const int wv   = tid >> 6;   // 0..7
    const int wr   = wv >> 2;    // M half (128 rows)
    const int wcn  = wv & 3;     // N quarter (64 cols)

    // staging decomposition: wave-load = 8 rows x 8 chunks(16B); source chunk pre-swizzled
    const int lrow8  = lane >> 3;
    const int gchunk = (lane & 7) ^ lrow8;
    const size_t aGR = (size_t)by * 256;
    const size_t bGR = (size_t)bx * 256;
    // B staging row bases (u2 covers rows {s*64+[0,32)}, u3 = +32)
    const int idx0 = wv * 2, idx1 = wv * 2 + 1;
    const int rB0 = (idx0 >> 2) * 64 + (idx0 & 3) * 8;
    const int rB1 = (idx1 >> 2) * 64 + (idx1 & 3) * 8;

    // fragment read bases; read-side swizzle: chunk = (kk*4 + lane>>4) ^ (row&7), row&7 == lane&7
    const int arBase = wr * 128 + (lane & 15);
    const int brBase = wcn * 64 + (lane & 15);
    const int csw0 = (((lane >> 4)) ^ (lane & 7)) * 8;
    const int csw1 = (((lane >> 4) + 4) ^ (lane & 7)) * 8;

    f32x4 acc[8][4];
#pragma unroll
    for (int m = 0; m < 8; ++m)
#pragma unroll
        for (int n = 0; n < 4; ++n) acc[m][n] = (f32x4){0.f, 0.f, 0.f, 0.f};

#define STAGE_A(bufw, r0, kc)                                                           \
    GLOAD_LDS16(X + ((aGR + (r0) + lrow8) << 10) + (kc) + gchunk * 8,                   \
                &lds[(bufw) + (unsigned)(r0) * 64])
#define STAGE_B(bufw, r0, kc)                                                           \
    GLOAD_LDS16(X + ((bGR + (r0) + lrow8) << 10) + (kc) + gchunk * 8,                   \
                &lds[(bufw) + 16384u + (unsigned)(r0) * 64])

    // prologue: stage tile 0's units in order u0(A,mq0) u2(B,nq0) u1(A,mq1) u3(B,nq1)
    STAGE_A(0u, wv * 8, 0);        STAGE_A(0u, 128 + wv * 8, 0);   // u0
    STAGE_B(0u, rB0, 0);           STAGE_B(0u, rB1, 0);            // u2
    STAGE_A(0u, 64 + wv * 8, 0);   STAGE_A(0u, 192 + wv * 8, 0);   // u1
    STAGE_B(0u, rB0 + 32, 0);      STAGE_B(0u, rB1 + 32, 0);       // u3
    asm volatile("s_waitcnt vmcnt(4)" ::: "memory");  // u0,u2 retired
    asm volatile("s_barrier" ::: "memory");

#define PHASE(PH, MQ, NQ, STAGE_STMT)                                                   \
    {                                                                                   \
        bf16x8 aF0[4], aF1[4], bF0[2], bF1[2];                                          \
        _Pragma("unroll")                                                               \
        for (int mf = 0; mf < 4; ++mf) {                                                \
            const unsigned r = bufR + (unsigned)(arBase + MQ * 64 + mf * 16) * 64;      \
            aF0[mf] = *reinterpret_cast<const bf16x8*>(&lds[r + csw0]);                 \
            aF1[mf] = *reinterpret_cast<const bf16x8*>(&lds[r + csw1]);                 \
        }                                                                               \
        _Pragma("unroll")                                                               \
        for (int nf = 0; nf < 2; ++nf) {                                                \
            const unsigned r = bufR + 16384u + (unsigned)(brBase + NQ * 32 + nf * 16) * 64; \
            bF0[nf] = *reinterpret_cast<const bf16x8*>(&lds[r + csw0]);                 \
            bF1[nf] = *reinterpret_cast<const bf16x8*>(&lds[r + csw1]);                 \
        }                                                                               \
        STAGE_STMT;                                                                     \
        asm volatile("s_barrier" ::: "memory");                                         \
        __builtin_amdgcn_s_setprio(1);                                                  \
        _Pragma("unroll")                                                               \
        for (int mf = 0; mf < 4; ++mf)                                                  \
            _Pragma("unroll")                                                           \
            for (int nf = 0; nf < 2; ++nf) {                                            \
                acc[MQ * 4 + mf][NQ * 2 + nf] = __builtin_amdgcn_mfma_f32_16x16x32_bf16( \
                    aF0[mf], bF0[nf], acc[MQ * 4 + mf][NQ * 2 + nf], 0, 0, 0);          \
                acc[MQ * 4 + mf][NQ * 2 + nf] = __builtin_amdgcn_mfma_f32_16x16x32_bf16( \
                    aF1[mf], bF1[nf], acc[MQ * 4 + mf][NQ * 2 + nf], 0, 0, 0);          \
            }                                                                           \
        __builtin_amdgcn_s_setprio(0);                                                  \
        if (haveNext) { asm volatile("s_waitcnt vmcnt(4)" ::: "memory"); }              \
        else if (PH == 0) { asm volatile("s_waitcnt vmcnt(0)" ::: "memory"); }          \
        asm volatile("s_barrier" ::: "memory");                                         \
    }

    for (int kt = 0; kt < NT; ++kt) {
        const bool haveNext = (kt + 1) < NT;
        const unsigned bufR = (kt & 1) ? 32768u : 0u;
        const unsigned bufW = ((kt + 1) & 1) ? 32768u : 0u;
        const int kc = (kt + 1) * 64;
        PHASE(0, 0, 0, if (haveNext) { STAGE_A(bufW, wv * 8, kc); STAGE_A(bufW, 128 + wv * 8, kc); })
        PHASE(1, 1, 0, if (haveNext) { STAGE_B(bufW, rB0, kc); STAGE_B(bufW, rB1, kc); })
        PHASE(2, 0, 1, if (haveNext) { STAGE_A(bufW, 64 + wv * 8, kc); STAGE_A(bufW, 192 + wv * 8, kc); })
        PHASE(3, 1, 1, if (haveNext) { STAGE_B(bufW, rB0 + 32, kc); STAGE_B(bufW, rB1 + 32, kc); })
    }

    // epilogue: C/D layout col = lane&15, row = (lane>>4)*4 + reg
    const int rbase = by * 256 + wr * 128;
    const int cbase = bx * 256 + wcn * 64;
    unsigned int* rm = rowmax + t * B_N;

    // row-max over this wave's 64 cols (diag excluded); union across waves via atomics
#pragma unroll
    for (int m = 0; m < 8; ++m) {
#pragma unroll
        for (int r = 0; r < 4; ++r) {
            const int row = rbase + m * 16 + (lane >> 4) * 4 + r;
            float mx = -2.0f;
#pragma unroll
            for (int n = 0; n < 4; ++n) {
                const int col = cbase + n * 16 + (lane & 15);
                float v = acc[m][n][r];
                if (col != row) mx = fmaxf(mx, v);
            }
#pragma unroll
            for (int off = 1; off < 16; off <<= 1) mx = fmaxf(mx, __shfl_xor(mx, off, 64));
            if ((lane & 15) == 0) atomicMax(&rm[row], f2u_ord(mx));
        }
    }
    // col-max over this wave's 128 rows (covers mirrored lower-triangle block)
#pragma unroll
    for (int n = 0; n < 4; ++n) {
        const int col = cbase + n * 16 + (lane & 15);
        float mx = -2.0f;
#pragma unroll
        for (int m = 0; m < 8; ++m)
#pragma unroll
            for (int r = 0; r < 4; ++r) {
                const int row = rbase + m * 16 + (lane >> 4) * 4 + r;
                float v = acc[m][n][r];
                if (col != row) mx = fmaxf(mx, v);
            }
        mx = fmaxf(mx, __shfl_xor(mx, 16, 64));
        mx = fmaxf(mx, __shfl_xor(mx, 32, 64));
        if ((lane >> 4) == 0) atomicMax(&rm[col], f2u_ord(mx));
    }
#undef PHASE
#undef STAGE_A
#undef STAGE_B
}

__global__ __launch_bounds__(256) void finish_kernel(const unsigned int* __restrict__ rowmax,
                                                     float* __restrict__ out) {
    __shared__ float sbuf[4];
    float s = 0.f;
    for (int i = threadIdx.x; i < T_N * B_N; i += 256) {
        float m  = u2f_ord(rowmax[i]);
        float d2 = fmaxf(2.0f - 2.0f * m, 0.0f);
        s += logf(sqrtf(d2) + 1e-12f);
    }
#pragma unroll
    for (int off = 32; off; off >>= 1) s += __shfl_xor(s, off, 64);
    const int w = threadIdx.x >> 6;
    if ((threadIdx.x & 63) == 0) sbuf[w] = s;
    __syncthreads();
    if (threadIdx.x == 0) {
        out[0] = -(sbuf[0] + sbuf[1] + sbuf[2] + sbuf[3]) / (float)(T_N * B_N);
    }
}

extern "C" void kernel_launch(void* const* d_in, const int* in_sizes, int n_in,
                              void* d_out, int out_size, void* d_ws, size_t ws_size,
                              hipStream_t stream) {
    const float* in = (const float*)d_in[0];
    unsigned short* xn = (unsigned short*)d_ws;  // 64 MB bf16 [T][B][D]
    unsigned int* rowmax = (unsigned int*)((char*)d_ws + (size_t)T_N * B_N * D_N * 2);
    float* out = (float*)d_out;

    init_rowmax_kernel<<<(T_N * B_N + 255) / 256, 256, 0, stream>>>(rowmax);
    norm_kernel<<<(B_N * T_N) / 4, 256, 0, stream>>>(in, xn);
    dim3 g(TRI, 1, T_N);
    gemm_rowmax_kernel<<<g, 512, 0, stream>>>(xn, rowmax);
    finish_kernel<<<1, 256, 0, stream>>>(rowmax, out);
}

// Round 4
// 406.873 us; speedup vs baseline: 1.7922x; 1.0809x over previous
//
#include <hip/hip_runtime.h>
#include <hip/hip_bf16.h>
#include <math.h>

#define B_N 8192
#define T_N 4
#define D_N 1024
#define NB  32                 // 8192/256 row/col blocks
#define NT  16                 // 1024/64 K-tiles
#define TRI (NB * (NB + 1) / 2)  // 528 upper-triangle blocks per view

typedef __bf16 bf16x8 __attribute__((ext_vector_type(8)));
typedef float f32x4 __attribute__((ext_vector_type(4)));

// ---- order-preserving float <-> uint map ----
__device__ inline unsigned int f2u_ord(float f) {
    unsigned int b = __float_as_uint(f);
    return (b & 0x80000000u) ? ~b : (b | 0x80000000u);
}
__device__ inline float u2f_ord(unsigned int u) {
    unsigned int b = (u & 0x80000000u) ? (u & 0x7FFFFFFFu) : ~u;
    return __uint_as_float(b);
}

// round-to-nearest-even f32 -> bf16
__device__ inline unsigned short f2bf(float f) {
    unsigned int u = __float_as_uint(f);
    unsigned int r = (u + 0x7FFFu + ((u >> 16) & 1u)) >> 16;
    return (unsigned short)r;
}

__global__ __launch_bounds__(256) void init_rowmax_kernel(unsigned int* __restrict__ rowmax) {
    int i = blockIdx.x * 256 + threadIdx.x;
    if (i < T_N * B_N) rowmax[i] = 0u;
}

// in: [B][T][D] f32 ; out xn: [T][B][D] bf16 (normalized rows)
__global__ __launch_bounds__(256) void norm_kernel(const float* __restrict__ in,
                                                   unsigned short* __restrict__ xn) {
    const int row  = blockIdx.x * 4 + (threadIdx.x >> 6);
    const int lane = threadIdx.x & 63;
    const int b = row >> 2;
    const int t = row & 3;
    const float* src = in + (size_t)row * D_N;

    float4 v[4];
    float ss = 0.f;
#pragma unroll
    for (int i = 0; i < 4; ++i) {
        v[i] = reinterpret_cast<const float4*>(src)[lane + 64 * i];
        ss += v[i].x * v[i].x + v[i].y * v[i].y + v[i].z * v[i].z + v[i].w * v[i].w;
    }
#pragma unroll
    for (int off = 32; off; off >>= 1) ss += __shfl_xor(ss, off, 64);
    const float rn = 1.0f / fmaxf(sqrtf(ss), 1e-12f);

    unsigned short* dst = xn + ((size_t)t * B_N + b) * D_N;
#pragma unroll
    for (int i = 0; i < 4; ++i) {
        ushort4 o;
        o.x = f2bf(v[i].x * rn);
        o.y = f2bf(v[i].y * rn);
        o.z = f2bf(v[i].z * rn);
        o.w = f2bf(v[i].w * rn);
        reinterpret_cast<ushort4*>(dst)[lane + 64 * i] = o;
    }
}

#define GLOAD_LDS16(g, l)                                                              \
    __builtin_amdgcn_global_load_lds(                                                  \
        (const __attribute__((address_space(1))) unsigned int*)(g),                    \
        (__attribute__((address_space(3))) unsigned int*)(l), 16, 0, 0)

// Gram matrix upper-triangle, 256x256 tile, BK=64, 8 waves (2M x 4N), 4-phase
// fragment-retention schedule: A-frags loaded once per MQ (reused 2 phases),
// B-frags loaded once per K-tile (retained). 24 ds_read_b128/wave/K-tile (min).
// Stage unit order u0,u2,u3,u1; counted vmcnt(4) gates exactly the unit the
// next phase reads. LDS chunk-XOR swizzle (chunk ^= row&7), source-side.
__global__ __launch_bounds__(512, 2) void gemm_rowmax_kernel(const unsigned short* __restrict__ xn,
                                                             unsigned int* __restrict__ rowmax) {
    const int t = blockIdx.z;
    // triangle decode: linear -> (by, bx), bx >= by
    int l = blockIdx.x, by = 0;
    while (l >= NB - by) { l -= NB - by; ++by; }
    const int bx = by + l;

    const unsigned short* X = xn + (size_t)t * B_N * D_N;

    __shared__ __align__(16) unsigned short lds[65536];  // 128 KiB: [2 buf][A 16K el | B 16K el]

    const int tid  = threadIdx.x;
    const int lane = tid & 63;
    const int wv   = tid >> 6;   // 0..7
    const int wr   = wv >> 2;    // M half (128 rows)
    const int wcn  = wv & 3;     // N quarter (64 cols)

    // staging: wave-load = 8 rows x 8 chunks(16B); source chunk pre-swizzled
    const int lrow8  = lane >> 3;
    const int gchunk = (lane & 7) ^ lrow8;
    const size_t aGR = (size_t)by * 256;
    const size_t bGR = (size_t)bx * 256;
    const int idx0 = wv * 2, idx1 = wv * 2 + 1;
    const int rB0 = (idx0 >> 2) * 64 + (idx0 & 3) * 8;
    const int rB1 = (idx1 >> 2) * 64 + (idx1 & 3) * 8;

    // fragment read bases; read-side swizzle: chunk = (kk) ^ (row&7), row&7 == lane&7
    const int arBase = wr * 128 + (lane & 15);
    const int brBase = wcn * 64 + (lane & 15);
    const int csw0 = (((lane >> 4)) ^ (lane & 7)) * 8;
    const int csw1 = (((lane >> 4) + 4) ^ (lane & 7)) * 8;

    f32x4 acc[8][4];
#pragma unroll
    for (int m = 0; m < 8; ++m)
#pragma unroll
        for (int n = 0; n < 4; ++n) acc[m][n] = (f32x4){0.f, 0.f, 0.f, 0.f};

#define STAGE_A(bufw, r0, kc)                                                           \
    GLOAD_LDS16(X + ((aGR + (r0) + lrow8) << 10) + (kc) + gchunk * 8,                   \
                &lds[(bufw) + (unsigned)(r0) * 64])
#define STAGE_B(bufw, r0, kc)                                                           \
    GLOAD_LDS16(X + ((bGR + (r0) + lrow8) << 10) + (kc) + gchunk * 8,                   \
                &lds[(bufw) + 16384u + (unsigned)(r0) * 64])

#define LOAD_A(MQ)                                                                      \
    _Pragma("unroll")                                                                   \
    for (int mf = 0; mf < 4; ++mf) {                                                    \
        const unsigned r = bufR + (unsigned)(arBase + (MQ) * 64 + mf * 16) * 64;        \
        aF0[mf] = *reinterpret_cast<const bf16x8*>(&lds[r + csw0]);                     \
        aF1[mf] = *reinterpret_cast<const bf16x8*>(&lds[r + csw1]);                     \
    }
#define LOAD_B(NQ)                                                                      \
    _Pragma("unroll")                                                                   \
    for (int nf = 0; nf < 2; ++nf) {                                                    \
        const unsigned r = bufR + 16384u + (unsigned)(brBase + (NQ) * 32 + nf * 16) * 64; \
        bF0[(NQ) * 2 + nf] = *reinterpret_cast<const bf16x8*>(&lds[r + csw0]);          \
        bF1[(NQ) * 2 + nf] = *reinterpret_cast<const bf16x8*>(&lds[r + csw1]);          \
    }
#define MFMA_Q(MQ, NQ)                                                                  \
    __builtin_amdgcn_s_setprio(1);                                                      \
    _Pragma("unroll")                                                                   \
    for (int mf = 0; mf < 4; ++mf)                                                      \
        _Pragma("unroll")                                                               \
        for (int nf = 0; nf < 2; ++nf) {                                                \
            acc[(MQ) * 4 + mf][(NQ) * 2 + nf] = __builtin_amdgcn_mfma_f32_16x16x32_bf16( \
                aF0[mf], bF0[(NQ) * 2 + nf], acc[(MQ) * 4 + mf][(NQ) * 2 + nf], 0, 0, 0); \
            acc[(MQ) * 4 + mf][(NQ) * 2 + nf] = __builtin_amdgcn_mfma_f32_16x16x32_bf16( \
                aF1[mf], bF1[(NQ) * 2 + nf], acc[(MQ) * 4 + mf][(NQ) * 2 + nf], 0, 0, 0); \
        }                                                                               \
    __builtin_amdgcn_s_setprio(0);

#define BARRIER asm volatile("s_barrier" ::: "memory")
#define VMCNT(N) asm volatile("s_waitcnt vmcnt(" #N ")" ::: "memory")

    // prologue: stage tile 0 units in issue order u0, u2, u3, u1
    STAGE_A(0u, wv * 8, 0);        STAGE_A(0u, 128 + wv * 8, 0);   // u0 (A MQ0)
    STAGE_B(0u, rB0, 0);           STAGE_B(0u, rB1, 0);            // u2 (B NQ0)
    STAGE_B(0u, rB0 + 32, 0);      STAGE_B(0u, rB1 + 32, 0);       // u3 (B NQ1)
    STAGE_A(0u, 64 + wv * 8, 0);   STAGE_A(0u, 192 + wv * 8, 0);   // u1 (A MQ1)
    VMCNT(4);  // u0,u2 retired
    BARRIER;

    for (int kt = 0; kt < NT; ++kt) {
        const bool haveNext = (kt + 1) < NT;
        const unsigned bufR = (kt & 1) ? 32768u : 0u;
        const unsigned bufW = ((kt + 1) & 1) ? 32768u : 0u;
        const int kc = (kt + 1) * 64;

        bf16x8 aF0[4], aF1[4], bF0[4], bF1[4];

        // ---- phase 1: (MQ0,NQ0); stage u0(next) ----
        LOAD_A(0); LOAD_B(0);
        if (haveNext) { STAGE_A(bufW, wv * 8, kc); STAGE_A(bufW, 128 + wv * 8, kc); }
        BARRIER;
        MFMA_Q(0, 0);
        if (haveNext) { VMCNT(4); } else { VMCNT(2); }  // u3(cur) retired
        BARRIER;

        // ---- phase 2: (MQ0,NQ1); stage u2(next) ----
        LOAD_B(1);
        if (haveNext) { STAGE_B(bufW, rB0, kc); STAGE_B(bufW, rB1, kc); }
        BARRIER;
        MFMA_Q(0, 1);
        if (haveNext) { VMCNT(4); } else { VMCNT(0); }  // u1(cur) retired
        BARRIER;

        // ---- phase 3: (MQ1,NQ0); stage u3(next) ----
        LOAD_A(1);
        if (haveNext) { STAGE_B(bufW, rB0 + 32, kc); STAGE_B(bufW, rB1 + 32, kc); }
        BARRIER;
        MFMA_Q(1, 0);
        BARRIER;  // phase 4 reads nothing new: no vmcnt

        // ---- phase 4: (MQ1,NQ1); stage u1(next) ----
        if (haveNext) { STAGE_A(bufW, 64 + wv * 8, kc); STAGE_A(bufW, 192 + wv * 8, kc); }
        BARRIER;
        MFMA_Q(1, 1);
        if (haveNext) { VMCNT(4); }  // u0,u2(next) retired
        BARRIER;
    }

    // epilogue: C/D layout col = lane&15, row = (lane>>4)*4 + reg
    const int rbase = by * 256 + wr * 128;
    const int cbase = bx * 256 + wcn * 64;
    unsigned int* rm = rowmax + t * B_N;

    // row-max over this wave's 64 cols (diag excluded)
#pragma unroll
    for (int m = 0; m < 8; ++m) {
#pragma unroll
        for (int r = 0; r < 4; ++r) {
            const int row = rbase + m * 16 + (lane >> 4) * 4 + r;
            float mx = -2.0f;
#pragma unroll
            for (int n = 0; n < 4; ++n) {
                const int col = cbase + n * 16 + (lane & 15);
                float v = acc[m][n][r];
                if (col != row) mx = fmaxf(mx, v);
            }
#pragma unroll
            for (int off = 1; off < 16; off <<= 1) mx = fmaxf(mx, __shfl_xor(mx, off, 64));
            if ((lane & 15) == 0) atomicMax(&rm[row], f2u_ord(mx));
        }
    }
    // col-max over this wave's 128 rows (covers mirrored lower-triangle block)
#pragma unroll
    for (int n = 0; n < 4; ++n) {
        const int col = cbase + n * 16 + (lane & 15);
        float mx = -2.0f;
#pragma unroll
        for (int m = 0; m < 8; ++m)
#pragma unroll
            for (int r = 0; r < 4; ++r) {
                const int row = rbase + m * 16 + (lane >> 4) * 4 + r;
                float v = acc[m][n][r];
                if (col != row) mx = fmaxf(mx, v);
            }
        mx = fmaxf(mx, __shfl_xor(mx, 16, 64));
        mx = fmaxf(mx, __shfl_xor(mx, 32, 64));
        if ((lane >> 4) == 0) atomicMax(&rm[col], f2u_ord(mx));
    }
#undef MFMA_Q
#undef LOAD_A
#undef LOAD_B
#undef STAGE_A
#undef STAGE_B
#undef BARRIER
#undef VMCNT
}

__global__ __launch_bounds__(256) void finish_kernel(const unsigned int* __restrict__ rowmax,
                                                     float* __restrict__ out) {
    __shared__ float sbuf[4];
    float s = 0.f;
    for (int i = threadIdx.x; i < T_N * B_N; i += 256) {
        float m  = u2f_ord(rowmax[i]);
        float d2 = fmaxf(2.0f - 2.0f * m, 0.0f);
        s += logf(sqrtf(d2) + 1e-12f);
    }
#pragma unroll
    for (int off = 32; off; off >>= 1) s += __shfl_xor(s, off, 64);
    const int w = threadIdx.x >> 6;
    if ((threadIdx.x & 63) == 0) sbuf[w] = s;
    __syncthreads();
    if (threadIdx.x == 0) {
        out[0] = -(sbuf[0] + sbuf[1] + sbuf[2] + sbuf[3]) / (float)(T_N * B_N);
    }
}

extern "C" void kernel_launch(void* const* d_in, const int* in_sizes, int n_in,
                              void* d_out, int out_size, void* d_ws, size_t ws_size,
                              hipStream_t stream) {
    const float* in = (const float*)d_in[0];
    unsigned short* xn = (unsigned short*)d_ws;  // 64 MB bf16 [T][B][D]
    unsigned int* rowmax = (unsigned int*)((char*)d_ws + (size_t)T_N * B_N * D_N * 2);
    float* out = (float*)d_out;

    init_rowmax_kernel<<<(T_N * B_N + 255) / 256, 256, 0, stream>>>(rowmax);
    norm_kernel<<<(B_N * T_N) / 4, 256, 0, stream>>>(in, xn);
    dim3 g(TRI, 1, T_N);
    gemm_rowmax_kernel<<<g, 512, 0, stream>>>(xn, rowmax);
    finish_kernel<<<1, 256, 0, stream>>>(rowmax, out);
}